// Round 6
// baseline (139.528 us; speedup 1.0000x reference)
//
#include <hip/hip_runtime.h>
#include <hip/hip_bf16.h>
#include <stdint.h>

#define B_  8
#define T_  2048
#define E_  512

typedef __attribute__((ext_vector_type(8))) __bf16 bf16x8;
typedef __attribute__((ext_vector_type(8))) unsigned short ushort8;
typedef __attribute__((ext_vector_type(4))) unsigned short ushort4v;
typedef __attribute__((ext_vector_type(4))) float f32x4;

__device__ __forceinline__ float bf2f(unsigned short u) {
  union { unsigned int u; float f; } c; c.u = ((unsigned int)u) << 16; return c.f;
}
__device__ __forceinline__ unsigned short f2bf(float f) {
  union { float f; unsigned int u; } c; c.f = f;
  unsigned int u = c.u;
  unsigned int r = (u + 0x7FFFu + ((u >> 16) & 1u)) >> 16;
  return (unsigned short)r;
}

__device__ __forceinline__ void gload_lds16(const void* g, void* l) {
  __builtin_amdgcn_global_load_lds(
      (const __attribute__((address_space(1))) uint32_t*)g,
      (__attribute__((address_space(3))) uint32_t*)l, 16, 0, 0);
}

// ---------------- fused bf16-convert + transpose ----------------
__global__ __launch_bounds__(256)
void trans_conv_kernel(const float* __restrict__ x, unsigned short* __restrict__ xbf,
                       unsigned short* __restrict__ xT) {
  __shared__ unsigned short tile[64][66];
  const int t0 = blockIdx.x * 64, e0 = blockIdx.y * 64, b = blockIdx.z;
  const int tid = threadIdx.x;
  const float* xb = x + ((size_t)b * T_ + t0) * E_ + e0;
  unsigned short* xbf_b = xbf + ((size_t)b * T_ + t0) * E_ + e0;
#pragma unroll
  for (int it = 0; it < 4; ++it) {
    int tr = (tid >> 4) + it * 16;
    int ec = (tid & 15) * 4;
    float4 f = *reinterpret_cast<const float4*>(xb + (size_t)tr * E_ + ec);
    ushort4v o;
    o[0] = f2bf(f.x); o[1] = f2bf(f.y); o[2] = f2bf(f.z); o[3] = f2bf(f.w);
    *reinterpret_cast<ushort4v*>(xbf_b + (size_t)tr * E_ + ec) = o;
    tile[ec + 0][tr] = o[0];
    tile[ec + 1][tr] = o[1];
    tile[ec + 2][tr] = o[2];
    tile[ec + 3][tr] = o[3];
  }
  __syncthreads();
  unsigned short* dst = xT + ((size_t)b * E_ + e0) * T_ + t0;
#pragma unroll
  for (int it = 0; it < 2; ++it) {
    int er = (tid >> 3) + it * 32;
    int tg = (tid & 7) * 8;
    ushort8 r;
#pragma unroll
    for (int j = 0; j < 8; ++j) r[j] = tile[er][tg + j];
    *reinterpret_cast<ushort8*>(dst + (size_t)er * T_ + tg) = r;
  }
}

// WT[n][kk] = (n<512 ? Wq[kk][n]*scale : Wk[kk][n-512]);  bqk[n] fused bias
__global__ __launch_bounds__(256)
void conv_w_kernel(const float* __restrict__ Wq, const float* __restrict__ Wk,
                   const float* __restrict__ bq, const float* __restrict__ bk,
                   unsigned short* __restrict__ WT, float* __restrict__ bqk, float scale) {
  int idx = blockIdx.x * 256 + threadIdx.x;
  int n  = idx >> 9;
  int kk = idx & 511;
  float v = (n < E_) ? Wq[kk * E_ + n] * scale : Wk[kk * E_ + (n - E_)];
  WT[idx] = f2bf(v);
  if (idx < 2 * E_) {
    float bv = (idx < E_) ? bq[idx] * scale : bk[idx - E_];
    bqk[idx] = bv;
  }
}

// ================= 128x128 GEMM, bf16 out, 2 blocks/CU =================
// 4 waves (2M x 2N), wave tile 64x64, BK=64, 64 KiB LDS dbuf, T2 swizzle.
// DO_EXP: epilogue exp + partial rowsum -> Rg.  Else: +bias[col].
// C written bf16 via LDS-staged coalesced ushort8 stores.
template<int DO_EXP>
__global__ __launch_bounds__(256)
void gemm128(const unsigned short* __restrict__ A, int lda, long long strA,
             const unsigned short* __restrict__ B, int ldb, long long strB,
             unsigned short* __restrict__ Cg, int ldc, long long strC,
             int K, const float* __restrict__ bias, int NBX, int NBY,
             float* __restrict__ Rg)
{
  __shared__ unsigned short sm[32768];   // 64 KiB
  const int tid  = threadIdx.x;
  const int lane = tid & 63;
  const int wv   = tid >> 6;
  const int wrp  = wv >> 1;
  const int wcp  = wv & 1;
  const int fr   = lane & 15;

  const int nwg = gridDim.x, bid = blockIdx.x;
  const int qq = nwg >> 3, rr = nwg & 7, xc = bid & 7, ii = bid >> 3;
  const int wg = (xc < rr ? xc * (qq + 1) : rr * (qq + 1) + (xc - rr) * qq) + ii;
  const int bx = wg % NBX;
  const int tt = wg / NBX;
  const int by = tt % NBY;
  const int bz = tt / NBY;

  const long long m0 = (long long)by * 128;
  const long long n0 = (long long)bx * 128;
  const unsigned short* Ab = A + (long long)bz * strA + m0 * lda;
  const unsigned short* Bb = B + (long long)bz * strB + n0 * ldb;

  const int srow = tid >> 3;
  const int scol = ((tid & 7) * 8) ^ ((srow & 7) << 3);
  const unsigned short* gA = Ab + (long long)srow * lda + scol;
  const unsigned short* gB = Bb + (long long)srow * ldb + scol;

  const int xorc  = (fr & 7) << 3;
  const int q8    = (lane >> 4) * 8;
  const int c0    = q8 ^ xorc;
  const int c1    = (32 + q8) ^ xorc;
  const int aRow  = (wrp * 64 + fr) * 64;
  const int bRow  = 8192 + (wcp * 64 + fr) * 64;

  f32x4 acc[4][4];
#pragma unroll
  for (int i = 0; i < 4; ++i)
#pragma unroll
    for (int j = 0; j < 4; ++j) acc[i][j] = (f32x4){0.f, 0.f, 0.f, 0.f};

  bf16x8 aA[4][2], bB2[2][2];
  const int NT = K >> 6;

#pragma unroll
  for (int r = 0; r < 4; ++r)
    gload_lds16(gA + (long long)(r * 32) * lda, &sm[r * 2048 + tid * 8]);
#pragma unroll
  for (int r = 0; r < 4; ++r)
    gload_lds16(gB + (long long)(r * 32) * ldb, &sm[8192 + r * 2048 + tid * 8]);
  asm volatile("s_waitcnt vmcnt(0)" ::: "memory");
  __builtin_amdgcn_s_barrier();

  int p = 0;
  for (int kt = 0; kt < NT; ++kt) {
    const int pb = p * 16384, pnb = pb ^ 16384;
    const long long koff = (long long)(kt + 1) * 64;
    // ---- phase 0 ----
#pragma unroll
    for (int m = 0; m < 4; ++m) {
      aA[m][0] = *reinterpret_cast<const bf16x8*>(&sm[pb + aRow + m * 1024 + c0]);
      aA[m][1] = *reinterpret_cast<const bf16x8*>(&sm[pb + aRow + m * 1024 + c1]);
    }
#pragma unroll
    for (int n = 0; n < 2; ++n) {
      bB2[n][0] = *reinterpret_cast<const bf16x8*>(&sm[pb + bRow + n * 1024 + c0]);
      bB2[n][1] = *reinterpret_cast<const bf16x8*>(&sm[pb + bRow + n * 1024 + c1]);
    }
    if (kt + 1 < NT) {
#pragma unroll
      for (int r = 0; r < 4; ++r)
        gload_lds16(gA + (long long)(r * 32) * lda + koff, &sm[pnb + r * 2048 + tid * 8]);
    }
    __builtin_amdgcn_s_barrier();
    __builtin_amdgcn_s_setprio(1);
#pragma unroll
    for (int m = 0; m < 4; ++m)
#pragma unroll
      for (int n = 0; n < 2; ++n) {
        acc[m][n] = __builtin_amdgcn_mfma_f32_16x16x32_bf16(aA[m][0], bB2[n][0], acc[m][n], 0, 0, 0);
        acc[m][n] = __builtin_amdgcn_mfma_f32_16x16x32_bf16(aA[m][1], bB2[n][1], acc[m][n], 0, 0, 0);
      }
    __builtin_amdgcn_s_setprio(0);
    __builtin_amdgcn_s_barrier();
    // ---- phase 1 ----
#pragma unroll
    for (int n = 0; n < 2; ++n) {
      bB2[n][0] = *reinterpret_cast<const bf16x8*>(&sm[pb + bRow + (2 + n) * 1024 + c0]);
      bB2[n][1] = *reinterpret_cast<const bf16x8*>(&sm[pb + bRow + (2 + n) * 1024 + c1]);
    }
    if (kt + 1 < NT) {
#pragma unroll
      for (int r = 0; r < 4; ++r)
        gload_lds16(gB + (long long)(r * 32) * ldb + koff, &sm[pnb + 8192 + r * 2048 + tid * 8]);
    }
    __builtin_amdgcn_s_barrier();
    __builtin_amdgcn_s_setprio(1);
#pragma unroll
    for (int m = 0; m < 4; ++m)
#pragma unroll
      for (int n = 0; n < 2; ++n) {
        acc[m][2 + n] = __builtin_amdgcn_mfma_f32_16x16x32_bf16(aA[m][0], bB2[n][0], acc[m][2 + n], 0, 0, 0);
        acc[m][2 + n] = __builtin_amdgcn_mfma_f32_16x16x32_bf16(aA[m][1], bB2[n][1], acc[m][2 + n], 0, 0, 0);
      }
    __builtin_amdgcn_s_setprio(0);
    asm volatile("s_waitcnt vmcnt(0)" ::: "memory");
    __builtin_amdgcn_s_barrier();
    p ^= 1;
  }

  // ---- epilogue ----
  const int rq = (lane >> 4) * 4;
  if (DO_EXP) {
#pragma unroll
    for (int m = 0; m < 4; ++m)
#pragma unroll
      for (int n = 0; n < 4; ++n)
#pragma unroll
        for (int j = 0; j < 4; ++j) acc[m][n][j] = __expf(acc[m][n][j]);
    // partial rowsum over this block's 128 cols
    float* rps = (float*)(sm + 17664);   // 256 f32, past the C-stage region
#pragma unroll
    for (int m = 0; m < 4; ++m)
#pragma unroll
      for (int j = 0; j < 4; ++j) {
        float s = acc[m][0][j] + acc[m][1][j] + acc[m][2][j] + acc[m][3][j];
        s += __shfl_xor(s, 1); s += __shfl_xor(s, 2);
        s += __shfl_xor(s, 4); s += __shfl_xor(s, 8);
        if (fr == 0) rps[wcp * 128 + wrp * 64 + m * 16 + rq + j] = s;
      }
  } else if (bias) {
#pragma unroll
    for (int n = 0; n < 4; ++n) {
      const float bv = bias[n0 + wcp * 64 + n * 16 + fr];
#pragma unroll
      for (int m = 0; m < 4; ++m)
#pragma unroll
        for (int j = 0; j < 4; ++j) acc[m][n][j] += bv;
    }
  }
  // C-stage into LDS (pad 136 shorts/row, 16B-aligned rows)
#pragma unroll
  for (int m = 0; m < 4; ++m)
#pragma unroll
    for (int j = 0; j < 4; ++j) {
      const int lrow = wrp * 64 + m * 16 + rq + j;
#pragma unroll
      for (int n = 0; n < 4; ++n)
        sm[lrow * 136 + wcp * 64 + n * 16 + fr] = f2bf(acc[m][n][j]);
    }
  __syncthreads();
  if (DO_EXP) {
    float* rps = (float*)(sm + 17664);
    if (tid < 128) {
      const float s = rps[tid] + rps[128 + tid];
      Rg[((long long)bz * NBX + bx) * 2048 + m0 + tid] = s;
    }
  }
  unsigned short* C = Cg + (long long)bz * strC;
#pragma unroll
  for (int it = 0; it < 8; ++it) {
    const int row = it * 16 + (tid >> 4);
    const int chunk = tid & 15;
    ushort8 v = *reinterpret_cast<const ushort8*>(&sm[row * 136 + chunk * 8]);
    *reinterpret_cast<ushort8*>(&C[(m0 + row) * ldc + n0 + chunk * 8]) = v;
  }
}

// ---------------- invR[b][t] = 1 / sum_c R[b][c][t]  (fixed order) ----------------
__global__ __launch_bounds__(256)
void rowsum_inv_kernel(const float* __restrict__ R, float* __restrict__ invR) {
  const int i = blockIdx.x * 256 + threadIdx.x;   // 0..16383
  const int b = i >> 11, t = i & 2047;
  float s = 0.f;
#pragma unroll
  for (int c = 0; c < 16; ++c) s += R[((long long)(b * 16 + c)) * 2048 + t];
  invR[i] = 1.0f / s;
}

// ================= PV GEMM: out = (P @ V) * invR =================
__global__ __launch_bounds__(256)
void gemm_pv2(const unsigned short* __restrict__ A, int lda, long long strA,
              const unsigned short* __restrict__ B, int ldb, long long strB,
              const float* __restrict__ invR,
              float* __restrict__ C, int ldc, long long strC, int K)
{
  __shared__ unsigned short sm[32768];
  const int tid  = threadIdx.x;
  const int lane = tid & 63;
  const int wv   = tid >> 6;
  const int wrp  = wv >> 1;
  const int wcp  = wv & 1;
  const int fr   = lane & 15;

  const int nwg = gridDim.x, bid = blockIdx.x;
  const int qq = nwg >> 3, rr = nwg & 7, xc = bid & 7, ii = bid >> 3;
  const int wg = (xc < rr ? xc * (qq + 1) : rr * (qq + 1) + (xc - rr) * qq) + ii;
  const int bx = wg & 3;
  const int by = (wg >> 2) & 15;
  const int bz = wg >> 6;

  const long long m0 = (long long)by * 128;
  const long long n0 = (long long)bx * 128;
  const unsigned short* Ab = A + (long long)bz * strA + m0 * lda;
  const unsigned short* Bb = B + (long long)bz * strB + n0 * ldb;

  const int srow = tid >> 3;
  const int scol = ((tid & 7) * 8) ^ ((srow & 7) << 3);
  const unsigned short* gA = Ab + (long long)srow * lda + scol;
  const unsigned short* gB = Bb + (long long)srow * ldb + scol;

  const int xorc  = (fr & 7) << 3;
  const int q8    = (lane >> 4) * 8;
  const int c0    = q8 ^ xorc;
  const int c1    = (32 + q8) ^ xorc;
  const int aRow  = (wrp * 64 + fr) * 64;
  const int bRow  = 8192 + (wcp * 64 + fr) * 64;

  f32x4 acc[4][4];
#pragma unroll
  for (int i = 0; i < 4; ++i)
#pragma unroll
    for (int j = 0; j < 4; ++j) acc[i][j] = (f32x4){0.f, 0.f, 0.f, 0.f};

  bf16x8 aA[4][2], bB2[2][2];
  const int NT = K >> 6;

#pragma unroll
  for (int r = 0; r < 4; ++r)
    gload_lds16(gA + (long long)(r * 32) * lda, &sm[r * 2048 + tid * 8]);
#pragma unroll
  for (int r = 0; r < 4; ++r)
    gload_lds16(gB + (long long)(r * 32) * ldb, &sm[8192 + r * 2048 + tid * 8]);
  asm volatile("s_waitcnt vmcnt(0)" ::: "memory");
  __builtin_amdgcn_s_barrier();

  int p = 0;
  for (int kt = 0; kt < NT; ++kt) {
    const int pb = p * 16384, pnb = pb ^ 16384;
    const long long koff = (long long)(kt + 1) * 64;
#pragma unroll
    for (int m = 0; m < 4; ++m) {
      aA[m][0] = *reinterpret_cast<const bf16x8*>(&sm[pb + aRow + m * 1024 + c0]);
      aA[m][1] = *reinterpret_cast<const bf16x8*>(&sm[pb + aRow + m * 1024 + c1]);
    }
#pragma unroll
    for (int n = 0; n < 2; ++n) {
      bB2[n][0] = *reinterpret_cast<const bf16x8*>(&sm[pb + bRow + n * 1024 + c0]);
      bB2[n][1] = *reinterpret_cast<const bf16x8*>(&sm[pb + bRow + n * 1024 + c1]);
    }
    if (kt + 1 < NT) {
#pragma unroll
      for (int r = 0; r < 4; ++r)
        gload_lds16(gA + (long long)(r * 32) * lda + koff, &sm[pnb + r * 2048 + tid * 8]);
    }
    __builtin_amdgcn_s_barrier();
    __builtin_amdgcn_s_setprio(1);
#pragma unroll
    for (int m = 0; m < 4; ++m)
#pragma unroll
      for (int n = 0; n < 2; ++n) {
        acc[m][n] = __builtin_amdgcn_mfma_f32_16x16x32_bf16(aA[m][0], bB2[n][0], acc[m][n], 0, 0, 0);
        acc[m][n] = __builtin_amdgcn_mfma_f32_16x16x32_bf16(aA[m][1], bB2[n][1], acc[m][n], 0, 0, 0);
      }
    __builtin_amdgcn_s_setprio(0);
    __builtin_amdgcn_s_barrier();
#pragma unroll
    for (int n = 0; n < 2; ++n) {
      bB2[n][0] = *reinterpret_cast<const bf16x8*>(&sm[pb + bRow + (2 + n) * 1024 + c0]);
      bB2[n][1] = *reinterpret_cast<const bf16x8*>(&sm[pb + bRow + (2 + n) * 1024 + c1]);
    }
    if (kt + 1 < NT) {
#pragma unroll
      for (int r = 0; r < 4; ++r)
        gload_lds16(gB + (long long)(r * 32) * ldb + koff, &sm[pnb + 8192 + r * 2048 + tid * 8]);
    }
    __builtin_amdgcn_s_barrier();
    __builtin_amdgcn_s_setprio(1);
#pragma unroll
    for (int m = 0; m < 4; ++m)
#pragma unroll
      for (int n = 0; n < 2; ++n) {
        acc[m][2 + n] = __builtin_amdgcn_mfma_f32_16x16x32_bf16(aA[m][0], bB2[n][0], acc[m][2 + n], 0, 0, 0);
        acc[m][2 + n] = __builtin_amdgcn_mfma_f32_16x16x32_bf16(aA[m][1], bB2[n][1], acc[m][2 + n], 0, 0, 0);
      }
    __builtin_amdgcn_s_setprio(0);
    asm volatile("s_waitcnt vmcnt(0)" ::: "memory");
    __builtin_amdgcn_s_barrier();
    p ^= 1;
  }

  const int rq = (lane >> 4) * 4;
  float* Cb = C + (long long)bz * strC;
#pragma unroll
  for (int m = 0; m < 4; ++m)
#pragma unroll
    for (int j = 0; j < 4; ++j) {
      const int lrow = wrp * 64 + m * 16 + rq + j;
      const long long row = m0 + lrow;
      const float inv = invR[bz * 2048 + row];
#pragma unroll
      for (int n = 0; n < 4; ++n)
        Cb[row * ldc + n0 + wcp * 64 + n * 16 + fr] = acc[m][n][j] * inv;
    }
}

// ---------------- launch ----------------
extern "C" void kernel_launch(void* const* d_in, const int* in_sizes, int n_in,
                              void* d_out, int out_size, void* d_ws, size_t ws_size,
                              hipStream_t stream)
{
  const float* x  = (const float*)d_in[0];
  const float* Wq = (const float*)d_in[1];
  const float* bq = (const float*)d_in[2];
  const float* Wk = (const float*)d_in[3];
  const float* bk = (const float*)d_in[4];
  float* out = (float*)d_out;

  char* w = (char*)d_ws;
  unsigned short* xbf  = (unsigned short*)w;  w += (size_t)B_ * T_ * E_ * 2;
  unsigned short* xT   = (unsigned short*)w;  w += (size_t)B_ * T_ * E_ * 2;
  unsigned short* WT   = (unsigned short*)w;  w += (size_t)2 * E_ * E_ * 2;
  float*          bqk  = (float*)w;           w += (size_t)2 * E_ * 4;
  float*          R    = (float*)w;           w += (size_t)B_ * 16 * T_ * 4;     // 2 MB
  float*          invR = (float*)w;           w += (size_t)B_ * T_ * 4;          // 64 KB
  unsigned short* qk   = (unsigned short*)w;  w += (size_t)B_ * T_ * 2 * E_ * 2;
  unsigned short* attn = (unsigned short*)w;  w += (size_t)B_ * T_ * T_ * 2;

  const float scale = 0.044194173824159216f;  // 512^-0.5

  trans_conv_kernel<<<dim3(32, 8, 8), 256, 0, stream>>>(x, xbf, xT);
  conv_w_kernel<<<2048, 256, 0, stream>>>(Wq, Wk, bq, bk, WT, bqk, scale);

  // qk[16384, 1024] = xbf @ WT^T (+bias)   grid 8x128 = 1024 blocks
  gemm128<0><<<1024, 256, 0, stream>>>(
      xbf, E_, 0, WT, E_, 0, qk, 2 * E_, 0, E_, bqk, 8, 128, nullptr);

  // P[b][2048,2048] = exp(q_b @ k_b^T) + partial rowsums   grid 16x16x8 = 2048
  gemm128<1><<<2048, 256, 0, stream>>>(
      qk, 2 * E_, (long long)T_ * 2 * E_,
      qk + E_, 2 * E_, (long long)T_ * 2 * E_,
      attn, T_, (long long)T_ * T_, E_, nullptr, 16, 16, R);

  rowsum_inv_kernel<<<64, 256, 0, stream>>>(R, invR);

  // out[b][2048,512] = (P_b @ x_b) * invR
  gemm_pv2<<<512, 256, 0, stream>>>(
      attn, T_, (long long)T_ * T_,
      xT, T_, (long long)E_ * T_,
      invR, out, E_, (long long)T_ * E_, T_);
}